// Round 2
// baseline (497.716 us; speedup 1.0000x reference)
//
#include <hip/hip_runtime.h>

// LightGCN, 3-layer propagation, 200001 nodes, D=64.
// Round 8: replace two-phase bucket CSR build (pass1_bucket ->
// bucket_arr -> build_csr_chunk) with direct per-row scatter:
//   count (2M atomics over 200K rows, ~10/addr contention,
//   fire-and-forget) -> chunk_sum -> scan_chunks -> row_scan
//   (row_ptr + in-place cursor) -> scatter (pos=atomicAdd(cursor)).
// Round 7 showed pass1 time scales with global-atomic chain length on
// the 391 shared bucket counters (489 blk/43us -> 1954 blk/103us at
// 79% occupancy, VALUBusy 1.2%): contention-bound, not wave-bound.
// Per-row counters drop contention to ~10/address and delete the
// 16MB-write + 16MB-read bucket_arr intermediate and a whole kernel.

#define N_NODES 200001
#define NUP1    100001            // NUM_USERS + 1
#define D       64
#define DV      16                // float4/ushort4 per row (init/final)
#define DV8     8                 // uint4 (8 bf16) per row (spmm)
#define CHUNK   512
#define NCHUNK  ((N_NODES + CHUNK - 1) / CHUNK)   // 391

__device__ __forceinline__ unsigned short f2bf(float f) {
  unsigned u = __float_as_uint(f);
  unsigned r = (u + 0x7FFFu + ((u >> 16) & 1u)) >> 16;   // RNE
  return (unsigned short)r;
}
__device__ __forceinline__ float bf2f(unsigned short h) {
  return __uint_as_float(((unsigned)h) << 16);
}
__device__ __forceinline__ float bflo(unsigned u) { return __uint_as_float(u << 16); }
__device__ __forceinline__ float bfhi(unsigned u) { return __uint_as_float(u & 0xFFFF0000u); }

// Build x0 (bf16) from fp32 embeddings; also zero per-row counts.
__global__ __launch_bounds__(256) void init_kernel(
    const float4* __restrict__ user_emb,
    const float4* __restrict__ item_emb,
    ushort4* __restrict__ x0,
    int* __restrict__ rc) {
  int idx = blockIdx.x * 256 + threadIdx.x;
  if (idx < N_NODES) rc[idx] = 0;
  if (idx >= N_NODES * DV) return;
  int n = idx >> 4;
  int j = idx & 15;
  float4 v = (n < NUP1) ? user_emb[idx]
                        : item_emb[(size_t)(n - 100000) * DV + j];
  x0[idx] = make_ushort4(f2bf(v.x), f2bf(v.y), f2bf(v.z), f2bf(v.w));
}

// Per-row histogram: 2M fire-and-forget atomics over 200K counters.
__global__ __launch_bounds__(256) void count_kernel(
    const int4* __restrict__ rows4, int* __restrict__ rc, int nnz) {
  int g = blockIdx.x * 256 + threadIdx.x;
  int e0 = g * 4;
  if (e0 + 3 < nnz) {
    int4 r = rows4[g];
    atomicAdd(&rc[r.x], 1);
    atomicAdd(&rc[r.y], 1);
    atomicAdd(&rc[r.z], 1);
    atomicAdd(&rc[r.w], 1);
  } else {
    const int* rows = (const int*)rows4;
    for (int e = e0; e < nnz; ++e) atomicAdd(&rc[rows[e]], 1);
  }
}

// Per-chunk sum of 512 row counts.
__global__ __launch_bounds__(512) void chunk_sum_kernel(
    const int* __restrict__ rc, int* __restrict__ chunk_cnt) {
  __shared__ int sh[512];
  int b = blockIdx.x, t = threadIdx.x;
  int row = b * CHUNK + t;
  sh[t] = (row < N_NODES) ? rc[row] : 0;
  __syncthreads();
  for (int o = 256; o > 0; o >>= 1) {
    if (t < o) sh[t] += sh[t + o];
    __syncthreads();
  }
  if (t == 0) chunk_cnt[b] = sh[0];
}

// Parallel exclusive scan of 391 chunk counts (one 512-thread block).
__global__ __launch_bounds__(512) void scan_chunks_kernel(
    const int* __restrict__ cnt, int* __restrict__ off,
    int* __restrict__ row_ptr, int nnz) {
  __shared__ int sh[512];
  int t = threadIdx.x;
  int v = (t < NCHUNK) ? cnt[t] : 0;
  sh[t] = v;
  __syncthreads();
  for (int o = 1; o < 512; o <<= 1) {
    int u = (t >= o) ? sh[t - o] : 0;
    __syncthreads();
    sh[t] += u;
    __syncthreads();
  }
  if (t < NCHUNK) off[t] = sh[t] - v;   // exclusive prefix
  if (t == 0) row_ptr[N_NODES] = nnz;
}

// Per-chunk scan of 512 row counts -> row_ptr; cursor written in place
// over rc (read-before-write is barrier-separated).
__global__ __launch_bounds__(512) void row_scan_kernel(
    int* __restrict__ rc, const int* __restrict__ chunk_off,
    int* __restrict__ row_ptr) {
  __shared__ int sh[512];
  int b = blockIdx.x, t = threadIdx.x;
  int row = b * CHUNK + t;
  int v = (row < N_NODES) ? rc[row] : 0;
  sh[t] = v;
  __syncthreads();
  for (int o = 1; o < 512; o <<= 1) {
    int u = (t >= o) ? sh[t - o] : 0;
    __syncthreads();
    sh[t] += u;
    __syncthreads();
  }
  if (row < N_NODES) {
    int p = chunk_off[b] + sh[t] - v;   // exclusive prefix within chunk
    row_ptr[row] = p;
    rc[row] = p;                        // becomes the scatter cursor
  }
}

// Direct scatter into final CSR order: pos = atomicAdd(cursor[row]).
__global__ __launch_bounds__(256) void scatter_kernel(
    const int4*   __restrict__ rows4,
    const int4*   __restrict__ cols4,
    const float4* __restrict__ vals4,
    int*  __restrict__ cursor,
    int2* __restrict__ edge_s, int nnz) {
  int g = blockIdx.x * 256 + threadIdx.x;
  int e0 = g * 4;
  if (e0 + 3 < nnz) {
    int4  r = rows4[g];
    int4  c = cols4[g];
    float4 v = vals4[g];
    int p0 = atomicAdd(&cursor[r.x], 1);
    int p1 = atomicAdd(&cursor[r.y], 1);
    int p2 = atomicAdd(&cursor[r.z], 1);
    int p3 = atomicAdd(&cursor[r.w], 1);
    edge_s[p0] = make_int2(c.x, __float_as_int(v.x));
    edge_s[p1] = make_int2(c.y, __float_as_int(v.y));
    edge_s[p2] = make_int2(c.z, __float_as_int(v.z));
    edge_s[p3] = make_int2(c.w, __float_as_int(v.w));
  } else {
    const int*   rows = (const int*)rows4;
    const int*   cols = (const int*)cols4;
    const float* vals = (const float*)vals4;
    for (int e = e0; e < nnz; ++e) {
      int p = atomicAdd(&cursor[rows[e]], 1);
      edge_s[p] = make_int2(cols[e], __float_as_int(vals[e]));
    }
  }
}

// Row-parallel bf16 SpMM: 8 lanes/row, 16 B (8 bf16 dims) per lane.
// Edge loop in clamped groups of 8: 8 record loads + 8 gathers issued
// back-to-back every iteration; padded slots contribute v=0.
__global__ __launch_bounds__(256) void spmm_bf16_kernel(
    const int*  __restrict__ row_ptr,
    const int2* __restrict__ edge_s,
    const uint4* __restrict__ x,
    uint4*       __restrict__ y) {
  int t = blockIdx.x * 256 + threadIdx.x;
  int r = t >> 3;
  int j = t & 7;
  if (r >= N_NODES) return;
  int s = row_ptr[r];
  int e = row_ptr[r + 1];
  float a0 = 0.f, a1 = 0.f, a2 = 0.f, a3 = 0.f;
  float a4 = 0.f, a5 = 0.f, a6 = 0.f, a7 = 0.f;
  int last = e - 1;
#define ACCUM(V, XV) {                                    \
    a0 += (V) * bflo((XV).x); a1 += (V) * bfhi((XV).x);   \
    a2 += (V) * bflo((XV).y); a3 += (V) * bfhi((XV).y);   \
    a4 += (V) * bflo((XV).z); a5 += (V) * bfhi((XV).z);   \
    a6 += (V) * bflo((XV).w); a7 += (V) * bfhi((XV).w); }
  for (int g = s; g < e; g += 8) {
    int2 e0 = edge_s[min(g + 0, last)];
    int2 e1 = edge_s[min(g + 1, last)];
    int2 e2 = edge_s[min(g + 2, last)];
    int2 e3 = edge_s[min(g + 3, last)];
    int2 e4 = edge_s[min(g + 4, last)];
    int2 e5 = edge_s[min(g + 5, last)];
    int2 e6 = edge_s[min(g + 6, last)];
    int2 e7 = edge_s[min(g + 7, last)];
    uint4 x0 = x[(size_t)e0.x * DV8 + j];
    uint4 x1 = x[(size_t)e1.x * DV8 + j];
    uint4 x2 = x[(size_t)e2.x * DV8 + j];
    uint4 x3 = x[(size_t)e3.x * DV8 + j];
    uint4 x4 = x[(size_t)e4.x * DV8 + j];
    uint4 x5 = x[(size_t)e5.x * DV8 + j];
    uint4 x6 = x[(size_t)e6.x * DV8 + j];
    uint4 x7 = x[(size_t)e7.x * DV8 + j];
    float v0 = __int_as_float(e0.y);
    float v1 = (g + 1 < e) ? __int_as_float(e1.y) : 0.f;
    float v2 = (g + 2 < e) ? __int_as_float(e2.y) : 0.f;
    float v3 = (g + 3 < e) ? __int_as_float(e3.y) : 0.f;
    float v4 = (g + 4 < e) ? __int_as_float(e4.y) : 0.f;
    float v5 = (g + 5 < e) ? __int_as_float(e5.y) : 0.f;
    float v6 = (g + 6 < e) ? __int_as_float(e6.y) : 0.f;
    float v7 = (g + 7 < e) ? __int_as_float(e7.y) : 0.f;
    ACCUM(v0, x0); ACCUM(v1, x1); ACCUM(v2, x2); ACCUM(v3, x3);
    ACCUM(v4, x4); ACCUM(v5, x5); ACCUM(v6, x6); ACCUM(v7, x7);
  }
#undef ACCUM
  uint4 o;
  o.x = ((unsigned)f2bf(a1) << 16) | f2bf(a0);
  o.y = ((unsigned)f2bf(a3) << 16) | f2bf(a2);
  o.z = ((unsigned)f2bf(a5) << 16) | f2bf(a4);
  o.w = ((unsigned)f2bf(a7) << 16) | f2bf(a6);
  y[t] = o;
}

// Final: out[rowmap(n)] = 0.25*(x0_fp32 + y1 + y2 + y3); zero item row 0.
__global__ __launch_bounds__(256) void final_kernel(
    const float4*  __restrict__ user_emb,
    const float4*  __restrict__ item_emb,
    const ushort4* __restrict__ y1,
    const ushort4* __restrict__ y2,
    const ushort4* __restrict__ y3,
    float4* __restrict__ out) {
  int idx = blockIdx.x * 256 + threadIdx.x;
  if (idx < DV) {
    out[(size_t)NUP1 * DV + idx] = make_float4(0.f, 0.f, 0.f, 0.f);
  }
  if (idx >= N_NODES * DV) return;
  int n = idx >> 4;
  int j = idx & 15;
  float4 v = (n < NUP1) ? user_emb[idx]
                        : item_emb[(size_t)(n - 100000) * DV + j];
  ushort4 a = y1[idx], b = y2[idx], c = y3[idx];
  float4 o;
  o.x = 0.25f * (v.x + bf2f(a.x) + bf2f(b.x) + bf2f(c.x));
  o.y = 0.25f * (v.y + bf2f(a.y) + bf2f(b.y) + bf2f(c.y));
  o.z = 0.25f * (v.z + bf2f(a.z) + bf2f(b.z) + bf2f(c.z));
  o.w = 0.25f * (v.w + bf2f(a.w) + bf2f(b.w) + bf2f(c.w));
  int rm = (n < NUP1) ? n : n + 1;
  out[(size_t)rm * DV + j] = o;
}

static inline char* align16(char* p) {
  return (char*)(((uintptr_t)p + 15) & ~(uintptr_t)15);
}

extern "C" void kernel_launch(void* const* d_in, const int* in_sizes, int n_in,
                              void* d_out, int out_size, void* d_ws, size_t ws_size,
                              hipStream_t stream) {
  const float* user_emb = (const float*)d_in[0];
  const float* item_emb = (const float*)d_in[1];
  const int*   rows     = (const int*)d_in[2];
  const int*   cols     = (const int*)d_in[3];
  const float* vals     = (const float*)d_in[4];
  const int    nnz      = in_sizes[2];

  const size_t xbytes = (size_t)N_NODES * D * sizeof(unsigned short); // 25.6 MB
  char* p = (char*)d_ws;
  ushort4* x0 = (ushort4*)p;  p += xbytes;
  ushort4* y1 = (ushort4*)p;  p += xbytes;
  ushort4* y2 = (ushort4*)p;  p += xbytes;
  ushort4* y3 = (ushort4*)p;  p += xbytes;
  p = align16(p);
  int2* edge_s = (int2*)p;    p += (size_t)nnz * sizeof(int2);
  p = align16(p);
  int* row_ptr = (int*)p;     p += (size_t)(N_NODES + 1) * sizeof(int);
  p = align16(p);
  int* rc = (int*)p;          p += (size_t)N_NODES * sizeof(int);   // counts -> cursor
  p = align16(p);
  int* chunk_off = (int*)p;   p += (size_t)NCHUNK * sizeof(int);
  p = align16(p);
  int* chunk_cnt = (int*)p;   p += (size_t)NCHUNK * sizeof(int);

  float* out = (float*)d_out;

  const int row_elems = N_NODES * DV;                // 3,200,016
  const int node_grid = (row_elems + 255) / 256;     // 12501
  const int spmm_grid = (N_NODES * DV8 + 255) / 256; // 6251
  const int quad_grid = ((nnz + 3) / 4 + 255) / 256; // 1954

  init_kernel<<<node_grid, 256, 0, stream>>>(
      (const float4*)user_emb, (const float4*)item_emb, x0, rc);
  count_kernel<<<quad_grid, 256, 0, stream>>>(
      (const int4*)rows, rc, nnz);
  chunk_sum_kernel<<<NCHUNK, 512, 0, stream>>>(rc, chunk_cnt);
  scan_chunks_kernel<<<1, 512, 0, stream>>>(chunk_cnt, chunk_off, row_ptr, nnz);
  row_scan_kernel<<<NCHUNK, 512, 0, stream>>>(rc, chunk_off, row_ptr);
  scatter_kernel<<<quad_grid, 256, 0, stream>>>(
      (const int4*)rows, (const int4*)cols, (const float4*)vals,
      rc, edge_s, nnz);

  spmm_bf16_kernel<<<spmm_grid, 256, 0, stream>>>(
      row_ptr, edge_s, (const uint4*)x0, (uint4*)y1);
  spmm_bf16_kernel<<<spmm_grid, 256, 0, stream>>>(
      row_ptr, edge_s, (const uint4*)y1, (uint4*)y2);
  spmm_bf16_kernel<<<spmm_grid, 256, 0, stream>>>(
      row_ptr, edge_s, (const uint4*)y2, (uint4*)y3);

  final_kernel<<<node_grid, 256, 0, stream>>>(
      (const float4*)user_emb, (const float4*)item_emb, y1, y2, y3,
      (float4*)out);
}

// Round 3
// 312.845 us; speedup vs baseline: 1.5909x; 1.5909x over previous
//
#include <hip/hip_runtime.h>

// LightGCN, 3-layer propagation, 200001 nodes, D=64.
// Round 9: revert to round-6 structure (best verified 323us; rounds
// 7/8 regressed: 4x blocks -> 4x atomic chain = 103us; direct scatter
// -> 126MB random 8B writes = 180us). Two local improvements:
//  (a) pass1 global bucket counters line-padded (64B apart) + 2
//      replicas by block parity: per-line atomic chain 489*16 -> 245.
//      Rounds 7/8 fit: t = 23us + 41ns * chain_depth -> predict ~29us.
//  (b) final_kernel fused into 3rd spmm (y3 stays fp32 in regs;
//      saves 51MB y3 HBM round-trip + one launch).

#define N_NODES 200001
#define NUP1    100001            // NUM_USERS + 1
#define D       64
#define DV      16                // float4/ushort4 per row (init/final)
#define DV8     8                 // uint4 (8 bf16) per row (spmm)
#define CHUNK   512
#define NCHUNK  ((N_NODES + CHUNK - 1) / CHUNK)   // 391
#define T_TILE  4096              // edges per pass1 block
#define EPT     16                // edges per thread in pass1
#define CAP     6144              // bucket capacity (exp ~5115, +14 sigma)
#define REP     2                 // counter replicas (by block parity)
#define HALFCAP (CAP / REP)       // 3072 (exp ~2558, +10 sigma)
#define CNT_STRIDE 16             // ints; one counter per 64B line
#define CNT_TOTAL  (NCHUNK * REP * CNT_STRIDE)   // 12512 ints

__device__ __forceinline__ unsigned short f2bf(float f) {
  unsigned u = __float_as_uint(f);
  unsigned r = (u + 0x7FFFu + ((u >> 16) & 1u)) >> 16;   // RNE
  return (unsigned short)r;
}
__device__ __forceinline__ float bf2f(unsigned short h) {
  return __uint_as_float(((unsigned)h) << 16);
}
__device__ __forceinline__ float bflo(unsigned u) { return __uint_as_float(u << 16); }
__device__ __forceinline__ float bfhi(unsigned u) { return __uint_as_float(u & 0xFFFF0000u); }

// Build x0 (bf16) from fp32 embeddings; also zero padded bucket counters.
__global__ __launch_bounds__(256) void init_kernel(
    const float4* __restrict__ user_emb,
    const float4* __restrict__ item_emb,
    ushort4* __restrict__ x0,
    int* __restrict__ bucket_cnt) {
  int idx = blockIdx.x * 256 + threadIdx.x;
  if (idx < CNT_TOTAL) bucket_cnt[idx] = 0;
  if (idx >= N_NODES * DV) return;
  int n = idx >> 4;
  int j = idx & 15;
  float4 v = (n < NUP1) ? user_emb[idx]
                        : item_emb[(size_t)(n - 100000) * DV + j];
  x0[idx] = make_ushort4(f2bf(v.x), f2bf(v.y), f2bf(v.z), f2bf(v.w));
}

// Pass 1: multisplit edges into 391 chunk-buckets (private per-block runs).
// Counter for (bucket b, replica r) at bucket_cnt[(b*REP+r)*CNT_STRIDE];
// replica r = blockIdx.x & 1 owns sub-region [b*CAP + r*HALFCAP, ...).
__global__ __launch_bounds__(256) void pass1_bucket(
    const int*   __restrict__ rows,
    const int*   __restrict__ cols,
    const float* __restrict__ vals,
    int*  __restrict__ bucket_cnt,
    int2* __restrict__ bucket_arr,
    int nnz) {
  __shared__ int lcount[NCHUNK];
  __shared__ int lbase[NCHUNK];
  int t = threadIdx.x;
  for (int i = t; i < NCHUNK; i += 256) lcount[i] = 0;
  __syncthreads();
  long base = (long)blockIdx.x * T_TILE;
  int rep = blockIdx.x & (REP - 1);
  int2 pk[EPT];
  int  meta[EPT];
#pragma unroll
  for (int k = 0; k < EPT; ++k) {
    long e = base + t + (long)k * 256;
    if (e < nnz) {
      int r = rows[e];
      int b = r >> 9;                          // chunk bucket (0..390)
      int rank = atomicAdd(&lcount[b], 1);     // LDS atomic
      pk[k] = make_int2(((r & 511) << 18) | cols[e], __float_as_int(vals[e]));
      meta[k] = (rank << 9) | b;               // rank<4096 (12b) | b (9b)
    } else {
      meta[k] = -1;
    }
  }
  __syncthreads();
  for (int b = t; b < NCHUNK; b += 256) {
    int c = lcount[b];
    lbase[b] = (c > 0)
        ? (b * CAP + rep * HALFCAP +
           atomicAdd(&bucket_cnt[(b * REP + rep) * CNT_STRIDE], c))
        : 0;
  }
  __syncthreads();
#pragma unroll
  for (int k = 0; k < EPT; ++k) {
    if (meta[k] >= 0) {
      int b = meta[k] & 511;
      int rank = meta[k] >> 9;
      bucket_arr[lbase[b] + rank] = pk[k];
    }
  }
}

// Parallel exclusive scan of 391 combined chunk counts (one block).
__global__ __launch_bounds__(512) void scan_chunks_kernel(
    const int* __restrict__ cnt, int* __restrict__ off,
    int* __restrict__ row_ptr, int nnz) {
  __shared__ int sh[512];
  int t = threadIdx.x;
  int v = (t < NCHUNK)
      ? cnt[(t * REP + 0) * CNT_STRIDE] + cnt[(t * REP + 1) * CNT_STRIDE]
      : 0;
  sh[t] = v;
  __syncthreads();
  for (int o = 1; o < 512; o <<= 1) {
    int u = (t >= o) ? sh[t - o] : 0;
    __syncthreads();
    sh[t] += u;
    __syncthreads();
  }
  if (t < NCHUNK) off[t] = sh[t] - v;   // exclusive prefix
  if (t == 0) row_ptr[N_NODES] = nnz;
}

// Fused per-chunk: LDS histogram -> LDS scan -> row_ptr write -> scatter
// into final CSR order with LDS cursors. Reads both replica segments.
__global__ __launch_bounds__(256) void build_csr_chunk(
    const int*  __restrict__ bucket_cnt,
    const int2* __restrict__ bucket_arr,
    const int*  __restrict__ chunk_off,
    int*  __restrict__ row_ptr,
    int2* __restrict__ edge_s) {
  __shared__ int lcnt[CHUNK];     // histogram, then cursors
  __shared__ int tsum[256];
  int b = blockIdx.x, t = threadIdx.x;
  lcnt[t] = 0; lcnt[t + 256] = 0;
  __syncthreads();
  int ne0 = bucket_cnt[(b * REP + 0) * CNT_STRIDE];
  int ne1 = bucket_cnt[(b * REP + 1) * CNT_STRIDE];
  const int2* ba = bucket_arr + (size_t)b * CAP;
  for (int i = t; i < ne0; i += 256)
    atomicAdd(&lcnt[ba[i].x >> 18], 1);
  for (int i = t; i < ne1; i += 256)
    atomicAdd(&lcnt[ba[HALFCAP + i].x >> 18], 1);
  __syncthreads();
  int base = t * 2;
  int l0 = lcnt[base], l1 = lcnt[base + 1];
  int s = l0 + l1;
  tsum[t] = s;
  __syncthreads();
  for (int o = 1; o < 256; o <<= 1) {
    int v = (t >= o) ? tsum[t - o] : 0;
    __syncthreads();
    tsum[t] += v;
    __syncthreads();
  }
  int run = tsum[t] - s + chunk_off[b];
  int row0 = b * CHUNK;
  if (row0 + base < N_NODES) row_ptr[row0 + base] = run;
  lcnt[base] = run;
  run += l0;
  if (row0 + base + 1 < N_NODES) row_ptr[row0 + base + 1] = run;
  lcnt[base + 1] = run;
  __syncthreads();
  for (int i = t; i < ne0; i += 256) {
    int2 ed = ba[i];
    int p = atomicAdd(&lcnt[ed.x >> 18], 1);
    edge_s[p] = make_int2(ed.x & 0x3FFFF, ed.y);
  }
  for (int i = t; i < ne1; i += 256) {
    int2 ed = ba[HALFCAP + i];
    int p = atomicAdd(&lcnt[ed.x >> 18], 1);
    edge_s[p] = make_int2(ed.x & 0x3FFFF, ed.y);
  }
}

// Row-parallel bf16 SpMM: 8 lanes/row, 16 B (8 bf16 dims) per lane.
// Edge loop in clamped groups of 8: 8 record loads + 8 gathers issued
// back-to-back every iteration; padded slots contribute v=0.
#define SPMM_BODY                                                   \
  int t = blockIdx.x * 256 + threadIdx.x;                           \
  int r = t >> 3;                                                   \
  int j = t & 7;                                                    \
  float a0 = 0.f, a1 = 0.f, a2 = 0.f, a3 = 0.f;                     \
  float a4 = 0.f, a5 = 0.f, a6 = 0.f, a7 = 0.f;                     \
  {                                                                 \
    int s = row_ptr[r];                                             \
    int e = row_ptr[r + 1];                                         \
    int last = e - 1;                                               \
    for (int g = s; g < e; g += 8) {                                \
      int2 e0 = edge_s[min(g + 0, last)];                           \
      int2 e1 = edge_s[min(g + 1, last)];                           \
      int2 e2 = edge_s[min(g + 2, last)];                           \
      int2 e3 = edge_s[min(g + 3, last)];                           \
      int2 e4 = edge_s[min(g + 4, last)];                           \
      int2 e5 = edge_s[min(g + 5, last)];                           \
      int2 e6 = edge_s[min(g + 6, last)];                           \
      int2 e7 = edge_s[min(g + 7, last)];                           \
      uint4 x0 = x[(size_t)e0.x * DV8 + j];                         \
      uint4 x1 = x[(size_t)e1.x * DV8 + j];                         \
      uint4 x2 = x[(size_t)e2.x * DV8 + j];                         \
      uint4 x3 = x[(size_t)e3.x * DV8 + j];                         \
      uint4 x4 = x[(size_t)e4.x * DV8 + j];                         \
      uint4 x5 = x[(size_t)e5.x * DV8 + j];                         \
      uint4 x6 = x[(size_t)e6.x * DV8 + j];                         \
      uint4 x7 = x[(size_t)e7.x * DV8 + j];                         \
      float v0 = __int_as_float(e0.y);                              \
      float v1 = (g + 1 < e) ? __int_as_float(e1.y) : 0.f;          \
      float v2 = (g + 2 < e) ? __int_as_float(e2.y) : 0.f;          \
      float v3 = (g + 3 < e) ? __int_as_float(e3.y) : 0.f;          \
      float v4 = (g + 4 < e) ? __int_as_float(e4.y) : 0.f;          \
      float v5 = (g + 5 < e) ? __int_as_float(e5.y) : 0.f;          \
      float v6 = (g + 6 < e) ? __int_as_float(e6.y) : 0.f;          \
      float v7 = (g + 7 < e) ? __int_as_float(e7.y) : 0.f;          \
      ACCUM(v0, x0); ACCUM(v1, x1); ACCUM(v2, x2); ACCUM(v3, x3);   \
      ACCUM(v4, x4); ACCUM(v5, x5); ACCUM(v6, x6); ACCUM(v7, x7);   \
    }                                                               \
  }

#define ACCUM(V, XV) {                                    \
    a0 += (V) * bflo((XV).x); a1 += (V) * bfhi((XV).x);   \
    a2 += (V) * bflo((XV).y); a3 += (V) * bfhi((XV).y);   \
    a4 += (V) * bflo((XV).z); a5 += (V) * bfhi((XV).z);   \
    a6 += (V) * bflo((XV).w); a7 += (V) * bfhi((XV).w); }

__global__ __launch_bounds__(256) void spmm_bf16_kernel(
    const int*  __restrict__ row_ptr,
    const int2* __restrict__ edge_s,
    const uint4* __restrict__ x,
    uint4*       __restrict__ y) {
  if ((blockIdx.x * 256 + threadIdx.x) >> 3 >= N_NODES) return;
  SPMM_BODY
  uint4 o;
  o.x = ((unsigned)f2bf(a1) << 16) | f2bf(a0);
  o.y = ((unsigned)f2bf(a3) << 16) | f2bf(a2);
  o.z = ((unsigned)f2bf(a5) << 16) | f2bf(a4);
  o.w = ((unsigned)f2bf(a7) << 16) | f2bf(a6);
  y[t] = o;
}

// Layer-3 SpMM fused with the final average:
// out[rowmap(r)] = 0.25*(emb_fp32 + y1 + y2 + a); y3 never materialized.
__global__ __launch_bounds__(256) void spmm_final_kernel(
    const int*  __restrict__ row_ptr,
    const int2* __restrict__ edge_s,
    const uint4* __restrict__ x,          // = y2 (gather input)
    const uint4* __restrict__ y1u,
    const float4* __restrict__ user_emb,
    const float4* __restrict__ item_emb,
    float4* __restrict__ out) {
  int gt = blockIdx.x * 256 + threadIdx.x;
  if (gt < DV) out[(size_t)NUP1 * DV + gt] = make_float4(0.f, 0.f, 0.f, 0.f);
  if (gt >> 3 >= N_NODES) return;
  SPMM_BODY
  uint4 w1 = y1u[(size_t)r * DV8 + j];
  uint4 w2 = x  [(size_t)r * DV8 + j];    // y2 row (x aliases y2)
  int rm = (r < NUP1) ? r : r + 1;
  size_t eb = (size_t)r * DV + 2 * j;
  float4 f0, f1;
  if (r < NUP1) {
    f0 = user_emb[eb];
    f1 = user_emb[eb + 1];
  } else {
    size_t ib = (size_t)(r - 100000) * DV + 2 * j;
    f0 = item_emb[ib];
    f1 = item_emb[ib + 1];
  }
  float4 o0, o1;
  o0.x = 0.25f * (f0.x + bflo(w1.x) + bflo(w2.x) + a0);
  o0.y = 0.25f * (f0.y + bfhi(w1.x) + bfhi(w2.x) + a1);
  o0.z = 0.25f * (f0.z + bflo(w1.y) + bflo(w2.y) + a2);
  o0.w = 0.25f * (f0.w + bfhi(w1.y) + bfhi(w2.y) + a3);
  o1.x = 0.25f * (f1.x + bflo(w1.z) + bflo(w2.z) + a4);
  o1.y = 0.25f * (f1.y + bfhi(w1.z) + bfhi(w2.z) + a5);
  o1.z = 0.25f * (f1.z + bflo(w1.w) + bflo(w2.w) + a6);
  o1.w = 0.25f * (f1.w + bfhi(w1.w) + bfhi(w2.w) + a7);
  out[(size_t)rm * DV + 2 * j]     = o0;
  out[(size_t)rm * DV + 2 * j + 1] = o1;
}
#undef ACCUM

static inline char* align16(char* p) {
  return (char*)(((uintptr_t)p + 15) & ~(uintptr_t)15);
}

extern "C" void kernel_launch(void* const* d_in, const int* in_sizes, int n_in,
                              void* d_out, int out_size, void* d_ws, size_t ws_size,
                              hipStream_t stream) {
  const float* user_emb = (const float*)d_in[0];
  const float* item_emb = (const float*)d_in[1];
  const int*   rows     = (const int*)d_in[2];
  const int*   cols     = (const int*)d_in[3];
  const float* vals     = (const float*)d_in[4];
  const int    nnz      = in_sizes[2];

  const size_t xbytes = (size_t)N_NODES * D * sizeof(unsigned short); // 25.6 MB
  char* p = (char*)d_ws;
  ushort4* x0 = (ushort4*)p;  p += xbytes;
  ushort4* y1 = (ushort4*)p;  p += xbytes;
  ushort4* y2 = (ushort4*)p;  p += xbytes;
  ushort4* y3 = (ushort4*)p;  p += xbytes;  // scratch window for bucket_arr
  // bucket_arr aliases y2+y3 (51.2 MB window; needs 19.2 MB): fully consumed
  // by build_csr_chunk before layer-2 spmm writes y2.
  int2* bucket_arr = (int2*)y2;
  (void)y3;
  p = align16(p);
  int2* edge_s = (int2*)p;    p += (size_t)nnz * sizeof(int2);
  p = align16(p);
  int* row_ptr = (int*)p;     p += (size_t)(N_NODES + 1) * sizeof(int);
  p = align16(p);
  int* chunk_off = (int*)p;   p += (size_t)NCHUNK * sizeof(int);
  p = align16(p);
  int* bucket_cnt = (int*)p;  p += (size_t)CNT_TOTAL * sizeof(int);

  float* out = (float*)d_out;

  const int row_elems = N_NODES * DV;                // 3,200,016
  const int node_grid = (row_elems + 255) / 256;     // 12501
  const int spmm_grid = (N_NODES * DV8 + 255) / 256; // 6251
  const int tile_grid = (nnz + T_TILE - 1) / T_TILE;

  init_kernel<<<node_grid, 256, 0, stream>>>(
      (const float4*)user_emb, (const float4*)item_emb, x0, bucket_cnt);
  pass1_bucket<<<tile_grid, 256, 0, stream>>>(
      rows, cols, vals, bucket_cnt, bucket_arr, nnz);
  scan_chunks_kernel<<<1, 512, 0, stream>>>(bucket_cnt, chunk_off, row_ptr, nnz);
  build_csr_chunk<<<NCHUNK, 256, 0, stream>>>(
      bucket_cnt, bucket_arr, chunk_off, row_ptr, edge_s);

  spmm_bf16_kernel<<<spmm_grid, 256, 0, stream>>>(
      row_ptr, edge_s, (const uint4*)x0, (uint4*)y1);
  spmm_bf16_kernel<<<spmm_grid, 256, 0, stream>>>(
      row_ptr, edge_s, (const uint4*)y1, (uint4*)y2);
  spmm_final_kernel<<<spmm_grid, 256, 0, stream>>>(
      row_ptr, edge_s, (const uint4*)y2, (const uint4*)y1,
      (const float4*)user_emb, (const float4*)item_emb, (float4*)out);
}